// Round 7
// baseline (14949.306 us; speedup 1.0000x reference)
//
#include <hip/hip_runtime.h>

// Problem dims
#define NB 64     // batch N
#define TS 512    // timesteps T
#define DI 512    // input I
#define DH 1024   // hidden H
#define DO 512    // output O

typedef __bf16 bf16x8 __attribute__((ext_vector_type(8)));
typedef float f32x4 __attribute__((ext_vector_type(4)));
typedef _Float16 f16x4 __attribute__((ext_vector_type(4)));
typedef int i32x4 __attribute__((ext_vector_type(4)));
typedef unsigned short u16x4 __attribute__((ext_vector_type(4)));

union V16 { i32x4 i; bf16x8 b; };

__device__ __forceinline__ float b2f(unsigned short u){
  union { unsigned int u; float f; } c; c.u = ((unsigned int)u) << 16; return c.f;
}
__device__ __forceinline__ unsigned short f2b(float f){
  union { float f; unsigned int u; } c; c.f = f;
  unsigned int x = c.u;
  return (unsigned short)((x + 0x7fffu + ((x >> 16) & 1u)) >> 16);
}

// ---------------------------------------------------------------------------
// C = A @ B^T + bias.  B: [NC][K] fp32 weights -> bf16-hi in LDS.
// AD: A dtype 0=fp32 (split hi/lo bf16, near-exact), 2=fp16 (split hi/lo,
// EXACT: fp16 mantissa 11b = bf16hi 8b + residual <=3b).
// mode (C-row q -> A-row remap): 0 rA=q | 1 C rows [T,N], A rows [N,T]
//   | 2 C rows [N,T], A rows [T,N]
// flags: bits0-1 out {0:f32, 2:f16}; bit2: retanh.
// Tile 128x128, BK=64, 256 thr, 2x2 waves of 64x64 (4x4 16x16x32 frags).
// Proven engine (rounds 3/4; bit-family-equivalent to clean-room rounds 5/6).
// ---------------------------------------------------------------------------
template<int AD>
__global__ __launch_bounds__(256) void gemm_bt(
    const void* __restrict__ Ain,
    const float* __restrict__ B,
    const float* __restrict__ bias,
    void* __restrict__ Cout,
    int K, int NC, int mode, int flags)
{
  __shared__ __align__(16) unsigned short As[2 * 128 * 72];
  __shared__ __align__(16) unsigned short Bs[128 * 72];
  constexpr int AS2 = 128 * 72;
  const int tid = threadIdx.x;
  const int q0 = blockIdx.y * 128;
  const int j0 = blockIdx.x * 128;
  const int w = tid >> 6, lane = tid & 63, quad = lane >> 4, lo4 = lane & 15;
  const int wm = w >> 1, wn = w & 1;
  f32x4 acc[4][4] = {};
  const int nkt = K >> 6;

  for (int kt = 0; kt < nkt; ++kt){
    __syncthreads();
    // B tile: 128 rows x 64 k, fp32 -> bf16 hi
    #pragma unroll
    for (int it = 0; it < 8; ++it){
      int idx = tid + it * 256;            // 2048 float4 chunks
      int row = idx >> 4, c4 = idx & 15;
      f32x4 f = *(const f32x4*)(B + (size_t)(j0 + row) * K + kt * 64 + c4 * 4);
      u16x4 h;
      #pragma unroll
      for (int j = 0; j < 4; ++j) h[j] = f2b(f[j]);
      *(u16x4*)(Bs + row * 72 + c4 * 4) = h;
    }
    // A tile: split hi/lo
    #pragma unroll
    for (int it = 0; it < 8; ++it){
      int idx = tid + it * 256;
      int row = idx >> 4, c4 = idx & 15;
      int q = q0 + row;
      int rA = (mode == 0) ? q : (mode == 1 ? (q & 63) * TS + (q >> 6)
                                            : (q & 511) * NB + (q >> 9));
      float fv[4];
      if (AD == 0){
        f32x4 f = *(const f32x4*)((const float*)Ain + (size_t)rA * K + kt * 64 + c4 * 4);
        #pragma unroll
        for (int j = 0; j < 4; ++j) fv[j] = f[j];
      } else {
        f16x4 f = *(const f16x4*)((const _Float16*)Ain + (size_t)rA * K + kt * 64 + c4 * 4);
        #pragma unroll
        for (int j = 0; j < 4; ++j) fv[j] = (float)f[j];
      }
      u16x4 hi, lo;
      #pragma unroll
      for (int j = 0; j < 4; ++j){
        unsigned short h = f2b(fv[j]);
        hi[j] = h;
        lo[j] = f2b(fv[j] - b2f(h));
      }
      *(u16x4*)(As + row * 72 + c4 * 4) = hi;
      *(u16x4*)(As + AS2 + row * 72 + c4 * 4) = lo;
    }
    __syncthreads();
    #pragma unroll
    for (int kk = 0; kk < 2; ++kk){
      V16 b[4];
      #pragma unroll
      for (int n = 0; n < 4; ++n)
        b[n].i = *(const i32x4*)(Bs + (64 * wn + 16 * n + lo4) * 72 + kk * 32 + quad * 8);
      V16 a[4], a2[4];
      #pragma unroll
      for (int m = 0; m < 4; ++m){
        a[m].i = *(const i32x4*)(As + (64 * wm + 16 * m + lo4) * 72 + kk * 32 + quad * 8);
        a2[m].i = *(const i32x4*)(As + AS2 + (64 * wm + 16 * m + lo4) * 72 + kk * 32 + quad * 8);
      }
      #pragma unroll
      for (int m = 0; m < 4; ++m)
        #pragma unroll
        for (int n = 0; n < 4; ++n){
          acc[m][n] = __builtin_amdgcn_mfma_f32_16x16x32_bf16(a[m].b, b[n].b, acc[m][n], 0, 0, 0);
          acc[m][n] = __builtin_amdgcn_mfma_f32_16x16x32_bf16(a2[m].b, b[n].b, acc[m][n], 0, 0, 0);
        }
    }
  }
  // epilogue: C/D layout col=lane&15, row=quad*4+reg  [m89]
  const int od = flags & 3;
  #pragma unroll
  for (int n = 0; n < 4; ++n){
    int col = j0 + 64 * wn + 16 * n + lo4;
    float bv = bias[col];
    #pragma unroll
    for (int m = 0; m < 4; ++m){
      int row = q0 + 64 * wm + 16 * m + quad * 4;
      #pragma unroll
      for (int r = 0; r < 4; ++r){
        float v = acc[m][n][r] + bv;
        if (flags & 4) v = tanhf(fmaxf(v, 0.0f));
        size_t o = (size_t)(row + r) * NC + col;
        if (od == 0) ((float*)Cout)[o] = v;
        else         ((_Float16*)Cout)[o] = (_Float16)v;
      }
    }
  }
}

// ---------------------------------------------------------------------------
// h0 fp32 -> hi/lo bf16 planes (65536 elements).
// ---------------------------------------------------------------------------
__global__ __launch_bounds__(256) void split_h0(
    const float* __restrict__ h0, unsigned short* __restrict__ plane)
{
  int i = blockIdx.x * 256 + threadIdx.x;
  float v = h0[i];
  unsigned short hb = f2b(v);
  plane[i] = hb;
  plane[65536 + i] = f2b(v - b2f(hb));
}

// ---------------------------------------------------------------------------
// One recurrence step (proven round-4 engine; hst now fp16):
// h_t = tanh(relu(x_t + h_{t-1} @ Wh^T + bh)); h and Wh hi/lo bf16 split,
// 3 MFMA chains -> near-fp32 exact. 64 WGs x 256 thr.
// ---------------------------------------------------------------------------
__global__ __launch_bounds__(256) void rnn_step(
    const _Float16* __restrict__ xt,        // [NB][DH] fp16
    const float* __restrict__ Wh,           // [DH][DH] fp32
    const float* __restrict__ bh,           // [DH] fp32
    const unsigned short* __restrict__ pin, // [2][NB][DH] hi/lo bf16
    unsigned short* __restrict__ pout,      // [2][NB][DH] hi/lo bf16
    _Float16* __restrict__ hst)             // [NB][DH] fp16
{
  __shared__ __align__(16) unsigned short WshH[16 * 1032];
  __shared__ __align__(16) unsigned short WshL[16 * 1032];
  const int g = blockIdx.x;
  const int tid = threadIdx.x;
  const int j0 = g * 16;
  const int w = tid >> 6, lane = tid & 63, quad = lane >> 4, lo4 = lane & 15;
  const int arow = 16 * w + lo4;
  const int col = j0 + lo4;
  const unsigned short* hp = pin;
  const unsigned short* lp = pin + 65536;

  i32x4 PH[16], PL[16];
  #pragma unroll
  for (int i = 0; i < 16; ++i){
    PH[i] = *(const i32x4*)(hp + (size_t)arow * 1024 + i * 32 + quad * 8);
    PL[i] = *(const i32x4*)(lp + (size_t)arow * 1024 + i * 32 + quad * 8);
  }
  float xv[4];
  #pragma unroll
  for (int r = 0; r < 4; ++r){
    int row = 16 * w + quad * 4 + r;
    xv[r] = (float)xt[row * 1024 + col];
  }
  const float bv = bh[col];

  for (int idx = tid; idx < 16 * 256; idx += 256){
    int j = idx >> 8, c4 = idx & 255;
    f32x4 f = *(const f32x4*)(Wh + (size_t)(j0 + j) * DH + c4 * 4);
    u16x4 hi, lo;
    #pragma unroll
    for (int e = 0; e < 4; ++e){
      unsigned short h = f2b(f[e]);
      hi[e] = h;
      lo[e] = f2b(f[e] - b2f(h));
    }
    *(u16x4*)(WshH + j * 1032 + c4 * 4) = hi;
    *(u16x4*)(WshL + j * 1032 + c4 * 4) = lo;
  }
  __syncthreads();

  f32x4 ah = {0.f, 0.f, 0.f, 0.f};
  #pragma unroll
  for (int kk = 0; kk < 32; ++kk){
    V16 va, vl, whi, wlo;
    va.i = PH[kk & 15]; vl.i = PL[kk & 15];
    if (kk < 16){
      PH[kk] = *(const i32x4*)(hp + (size_t)arow * 1024 + (kk + 16) * 32 + quad * 8);
      PL[kk] = *(const i32x4*)(lp + (size_t)arow * 1024 + (kk + 16) * 32 + quad * 8);
    }
    whi.i = *(const i32x4*)(WshH + lo4 * 1032 + kk * 32 + quad * 8);
    wlo.i = *(const i32x4*)(WshL + lo4 * 1032 + kk * 32 + quad * 8);
    ah = __builtin_amdgcn_mfma_f32_16x16x32_bf16(va.b, whi.b, ah, 0, 0, 0);
    ah = __builtin_amdgcn_mfma_f32_16x16x32_bf16(vl.b, whi.b, ah, 0, 0, 0);
    ah = __builtin_amdgcn_mfma_f32_16x16x32_bf16(va.b, wlo.b, ah, 0, 0, 0);
  }

  #pragma unroll
  for (int r = 0; r < 4; ++r){
    int row = 16 * w + quad * 4 + r;
    float v = ah[r] + xv[r] + bv;
    v = tanhf(fmaxf(v, 0.0f));
    int off = row * 1024 + col;
    hst[off] = (_Float16)v;
    unsigned short hb = f2b(v);
    pout[off] = hb;
    pout[65536 + off] = f2b(v - b2f(hb));
  }
}

// ---------------------------------------------------------------------------
// Workspace (~128.6 MB, proven mapped; ws almost certainly 256 MiB):
//   REG0 (64 MiB)   : inp_v fp16 -> out_v fp32 -> inp_m fp16
//   REG1 (64 MiB)   : hs_v fp16 -> out_t fp32 -> hs_m fp16
//   PLANES (512 KiB): h hi/lo bf16 double-buffered
// d_out: FP32 [N][T][O] (reference output dtype is float32).
// ---------------------------------------------------------------------------
extern "C" void kernel_launch(void* const* d_in, const int* in_sizes, int n_in,
                              void* d_out, int out_size, void* d_ws, size_t ws_size,
                              hipStream_t stream)
{
  const float* data = (const float*)d_in[0];
  const float* h0v  = (const float*)d_in[1];
  const float* h0m  = (const float*)d_in[2];
  const float* Wi   = (const float*)d_in[3];
  const float* bi   = (const float*)d_in[4];
  const float* Wh   = (const float*)d_in[5];
  const float* bh   = (const float*)d_in[6];
  const float* Wo   = (const float*)d_in[7];
  const float* bo   = (const float*)d_in[8];
  const float* Wt   = (const float*)d_in[9];
  const float* bt   = (const float*)d_in[10];
  const float* Wi2  = (const float*)d_in[11];
  const float* bi2  = (const float*)d_in[12];
  const float* Wh2  = (const float*)d_in[13];
  const float* bh2  = (const float*)d_in[14];
  const float* Wo2  = (const float*)d_in[15];
  const float* bo2  = (const float*)d_in[16];

  char* base = (char*)d_ws;
  char* REG0 = base + 4096;
  char* REG1 = base + 4096 + (size_t)67108864;
  unsigned short* PLANES = (unsigned short*)(base + 4096 + (size_t)134217728);

  dim3 blk(256, 1, 1);

  // 1) inp_v[t,n,h] = data[n,t,:] @ Wi^T + bi  (A fp32-split, out fp16) -> REG0
  gemm_bt<0><<<dim3(8, 256, 1), blk, 0, stream>>>(data, Wi, bi, REG0, DI, DH, 1, 2);

  // 2) visual recurrence (per-step dispatch, proven)
  split_h0<<<dim3(256, 1, 1), blk, 0, stream>>>(h0v, PLANES);
  for (int t = 0; t < TS; ++t){
    const unsigned short* pin = PLANES + (t & 1) * 131072;
    unsigned short* pout = PLANES + ((t + 1) & 1) * 131072;
    rnn_step<<<dim3(64, 1, 1), blk, 0, stream>>>(
        (const _Float16*)REG0 + (size_t)t * 65536, Wh, bh, pin, pout,
        (_Float16*)REG1 + (size_t)t * 65536);
  }

  // 3) out_v[n,t,o] = hs_v[t,n,:] @ Wo^T + bo  (A fp16-split, out fp32) -> REG0
  gemm_bt<2><<<dim3(4, 256, 1), blk, 0, stream>>>(REG1, Wo, bo, REG0, DH, DO, 2, 0);

  // 4) out_t = retanh(out_v @ Wt^T + bt)       (A fp32-split, out fp32) -> REG1
  gemm_bt<0><<<dim3(4, 256, 1), blk, 0, stream>>>(REG0, Wt, bt, REG1, DO, DO, 0, 4);

  // 5) inp_m[t,n,h] = out_t[n,t,:] @ Wi2^T + bi2 (A fp32-split, out fp16) -> REG0
  gemm_bt<0><<<dim3(8, 256, 1), blk, 0, stream>>>(REG1, Wi2, bi2, REG0, DO, DH, 1, 2);

  // 6) motor recurrence
  split_h0<<<dim3(256, 1, 1), blk, 0, stream>>>(h0m, PLANES);
  for (int t = 0; t < TS; ++t){
    const unsigned short* pin = PLANES + (t & 1) * 131072;
    unsigned short* pout = PLANES + ((t + 1) & 1) * 131072;
    rnn_step<<<dim3(64, 1, 1), blk, 0, stream>>>(
        (const _Float16*)REG0 + (size_t)t * 65536, Wh2, bh2, pin, pout,
        (_Float16*)REG1 + (size_t)t * 65536);
  }

  // 7) out_m[n,t,o] = hs_m[t,n,:] @ Wo2^T + bo2 (A fp16-split, OUT FP32) -> d_out
  gemm_bt<2><<<dim3(4, 256, 1), blk, 0, stream>>>(REG1, Wo2, bo2, d_out, DH, DO, 2, 0);
}